// Round 1
// baseline (991.903 us; speedup 1.0000x reference)
//
#include <hip/hip_runtime.h>
#include <math.h>

// Problem constants (match reference)
#define NUM_HEADS 32
#define KV_HEADS 8
#define GROUPS 4            // NUM_HEADS / KV_HEADS
#define HEAD_DIM 128
#define BLOCK_SIZE 16
#define MAX_CTX 2048
#define BSZ 64
#define BLOCKS_PER_SEQ 128  // MAX_CTX / BLOCK_SIZE

// Flash-decoding split
#define CHUNK_BLOCKS 16                 // KV blocks per chunk
#define CHUNK_TOKENS (CHUNK_BLOCKS * BLOCK_SIZE)   // 256
#define NCHUNK (MAX_CTX / CHUNK_TOKENS)            // 8
#define REC_STRIDE 520                  // 4*128 o + 4 m + 4 l floats per partial record

// ---------------------------------------------------------------------------
// Kernel 1: per-(seq, kvh, chunk) partial attention with online softmax.
// 256 threads = 4 waves; wave w handles blocks bstart+w, +4, +8, +12.
// Within a wave: iteration `it` covers tokens 2it (lanes 0..31) and 2it+1
// (lanes 32..63); lane's float4 = dims [4c,4c+4) with c = lane&31. Every
// global_load_dwordx4 of a wave is a contiguous 1 KB => fully coalesced.
// ---------------------------------------------------------------------------
__global__ __launch_bounds__(256, 4)
void attn_partial_kernel(const float* __restrict__ q,
                         const float* __restrict__ kcache,
                         const float* __restrict__ vcache,
                         const int*   __restrict__ btab,
                         const int*   __restrict__ lens,
                         float*       __restrict__ part)
{
    const int chunk = blockIdx.x;
    const int kvh   = blockIdx.y;
    const int seq   = blockIdx.z;

    const int len  = lens[seq];
    const int tok0 = chunk * CHUNK_TOKENS;
    if (tok0 >= len) return;                 // dead chunk, never read by reducer

    const int tid  = threadIdx.x;
    const int wave = tid >> 6;
    const int lane = tid & 63;
    const int half = lane >> 5;              // token parity handled by this lane
    const int c    = lane & 31;              // float4 chunk of the 128 dims

    const float scale = 0.08838834764831845f; // 1/sqrt(128)

    // q fragments for the 4 query heads of this kv head, pre-scaled
    float4 qv[GROUPS];
    const float* qbase = q + ((size_t)seq * NUM_HEADS + (size_t)kvh * GROUPS) * HEAD_DIM + c * 4;
#pragma unroll
    for (int h = 0; h < GROUPS; ++h) {
        float4 t = *(const float4*)(qbase + h * HEAD_DIM);
        qv[h] = make_float4(t.x * scale, t.y * scale, t.z * scale, t.w * scale);
    }

    // per-half-wave online-softmax state (m,l uniform across the 32 lanes)
    float  m[GROUPS], l[GROUPS];
    float4 o[GROUPS];
#pragma unroll
    for (int h = 0; h < GROUPS; ++h) {
        m[h] = -INFINITY; l[h] = 0.f; o[h] = make_float4(0.f, 0.f, 0.f, 0.f);
    }

    const int nblk   = (len + BLOCK_SIZE - 1) / BLOCK_SIZE;
    const int bstart = chunk * CHUNK_BLOCKS;
    const int bend   = min(bstart + CHUNK_BLOCKS, nblk);

    for (int b = bstart + wave; b < bend; b += 4) {
        const int phys = btab[seq * BLOCKS_PER_SEQ + b];
        const size_t slice = ((size_t)phys * KV_HEADS + kvh) * (BLOCK_SIZE * HEAD_DIM);
        const float* kblk = kcache + slice;
        const float* vblk = vcache + slice;
        const int tbase = b * BLOCK_SIZE;

#pragma unroll
        for (int it = 0; it < 8; ++it) {
            const int off = (it * 64 + lane) * 4;
            float4 k4 = *(const float4*)(kblk + off);
            float4 v4 = *(const float4*)(vblk + off);
            const bool valid = (tbase + 2 * it + half) < len;

            // q·k partial -> butterfly reduce within each 32-lane half
            float s[GROUPS];
#pragma unroll
            for (int h = 0; h < GROUPS; ++h) {
                float p = k4.x * qv[h].x + k4.y * qv[h].y + k4.z * qv[h].z + k4.w * qv[h].w;
#pragma unroll
                for (int d = 1; d < 32; d <<= 1)
                    p += __shfl_xor(p, d, 64);
                s[h] = p;                    // uniform over the half-wave
            }

            if (valid) {
#pragma unroll
                for (int h = 0; h < GROUPS; ++h) {
                    float mn    = fmaxf(m[h], s[h]);          // finite (s finite)
                    float alpha = __expf(m[h] - mn);          // exp(-inf)=0 on first hit
                    float p     = __expf(s[h] - mn);
                    l[h] = l[h] * alpha + p;
                    o[h].x = o[h].x * alpha + p * v4.x;
                    o[h].y = o[h].y * alpha + p * v4.y;
                    o[h].z = o[h].z * alpha + p * v4.z;
                    o[h].w = o[h].w * alpha + p * v4.w;
                    m[h] = mn;
                }
            }
        }
    }

    // ---- merge the two half-wave states within each wave (xor 32) ----
#pragma unroll
    for (int h = 0; h < GROUPS; ++h) {
        float mo = __shfl_xor(m[h], 32, 64);
        float m2 = fmaxf(m[h], mo);
        float w  = (m[h] == -INFINITY) ? 0.f : __expf(m[h] - m2);
        float ls = l[h] * w;
        l[h] = ls + __shfl_xor(ls, 32, 64);
        o[h].x *= w; o[h].y *= w; o[h].z *= w; o[h].w *= w;
        o[h].x += __shfl_xor(o[h].x, 32, 64);
        o[h].y += __shfl_xor(o[h].y, 32, 64);
        o[h].z += __shfl_xor(o[h].z, 32, 64);
        o[h].w += __shfl_xor(o[h].w, 32, 64);
        m[h] = m2;                            // may be -inf if wave saw no tokens
    }

    // ---- merge the 4 waves through LDS ----
    __shared__ float o_lds[4][GROUPS][HEAD_DIM];  // 8 KB
    __shared__ float m_lds[4][GROUPS];
    __shared__ float l_lds[4][GROUPS];
    if (half == 0) {
#pragma unroll
        for (int h = 0; h < GROUPS; ++h)
            *(float4*)&o_lds[wave][h][c * 4] = o[h];
        if (c == 0) {
#pragma unroll
            for (int h = 0; h < GROUPS; ++h) { m_lds[wave][h] = m[h]; l_lds[wave][h] = l[h]; }
        }
    }
    __syncthreads();

    float* rec = part + (((size_t)(seq * KV_HEADS + kvh)) * NCHUNK + chunk) * REC_STRIDE;
#pragma unroll
    for (int r = 0; r < 2; ++r) {
        const int e = tid + r * 256;          // 0..511 over (head, dim)
        const int h = e >> 7;
        const int d = e & 127;
        float mstar = fmaxf(fmaxf(m_lds[0][h], m_lds[1][h]),
                            fmaxf(m_lds[2][h], m_lds[3][h]));   // finite: wave0 saw token tok0
        float num = 0.f, L = 0.f;
#pragma unroll
        for (int w = 0; w < 4; ++w) {
            float mw = m_lds[w][h];
            float ww = (mw == -INFINITY) ? 0.f : __expf(mw - mstar);
            num += o_lds[w][h][d] * ww;
            L   += l_lds[w][h] * ww;
        }
        rec[e] = num;                         // unnormalized output
        if (d == 0) { rec[512 + h] = mstar; rec[516 + h] = L; }
    }
}

// ---------------------------------------------------------------------------
// Kernel 2: merge the <=8 chunk partials per (seq, kvh) and normalize.
// ---------------------------------------------------------------------------
__global__ __launch_bounds__(256)
void attn_reduce_kernel(const float* __restrict__ part,
                        const int*   __restrict__ lens,
                        float*       __restrict__ out)
{
    const int kvh = blockIdx.x & (KV_HEADS - 1);
    const int seq = blockIdx.x / KV_HEADS;
    const int len = lens[seq];
    const int nlive = (len + CHUNK_TOKENS - 1) / CHUNK_TOKENS;   // >= 1

    const float* base = part + ((size_t)(seq * KV_HEADS + kvh)) * NCHUNK * REC_STRIDE;
    const int tid = threadIdx.x;

#pragma unroll
    for (int r = 0; r < 2; ++r) {
        const int e = tid + r * 256;
        const int h = e >> 7;
        const int d = e & 127;

        float mstar = -INFINITY;
        for (int ch = 0; ch < nlive; ++ch)
            mstar = fmaxf(mstar, base[ch * REC_STRIDE + 512 + h]);

        float num = 0.f, L = 0.f;
        for (int ch = 0; ch < nlive; ++ch) {
            const float* r0 = base + ch * REC_STRIDE;
            float ww = __expf(r0[512 + h] - mstar);   // live chunks have finite m
            num += r0[e] * ww;
            L   += r0[516 + h] * ww;
        }
        out[(size_t)seq * (NUM_HEADS * HEAD_DIM) + (kvh * GROUPS + h) * HEAD_DIM + d] = num / L;
    }
}

extern "C" void kernel_launch(void* const* d_in, const int* in_sizes, int n_in,
                              void* d_out, int out_size, void* d_ws, size_t ws_size,
                              hipStream_t stream) {
    const float* q    = (const float*)d_in[0];
    const float* kc   = (const float*)d_in[1];
    const float* vc   = (const float*)d_in[2];
    const int*   bt   = (const int*)d_in[3];
    const int*   lens = (const int*)d_in[4];
    float* out  = (float*)d_out;
    float* part = (float*)d_ws;   // 64*8*8*520*4 B = 8.5 MB of scratch

    dim3 g1(NCHUNK, KV_HEADS, BSZ);
    attn_partial_kernel<<<g1, 256, 0, stream>>>(q, kc, vc, bt, lens, part);

    dim3 g2(BSZ * KV_HEADS);
    attn_reduce_kernel<<<g2, 256, 0, stream>>>(part, lens, out);
}

// Round 2
// 939.615 us; speedup vs baseline: 1.0556x; 1.0556x over previous
//
#include <hip/hip_runtime.h>
#include <math.h>

// Problem constants (match reference)
#define NUM_HEADS 32
#define KV_HEADS 8
#define GROUPS 4            // NUM_HEADS / KV_HEADS
#define HEAD_DIM 128
#define BLOCK_SIZE 16
#define MAX_CTX 2048
#define BSZ 64
#define BLOCKS_PER_SEQ 128  // MAX_CTX / BLOCK_SIZE

// Flash-decoding split
#define CHUNK_BLOCKS 16
#define CHUNK_TOKENS (CHUNK_BLOCKS * BLOCK_SIZE)   // 256
#define NCHUNK (MAX_CTX / CHUNK_TOKENS)            // 8
#define REC_STRIDE 520      // 4*128 o + 4 m + 4 l floats per partial record

// ---------------------------------------------------------------------------
// Kernel 1: per-(seq, kvh, chunk) partials. 256 threads = 4 waves; wave w
// handles blocks bstart+w, +4, +8, +12. Lane layout: lane = 16*g + u.
// Token group g in [0,4) owns tokens 4j+g of each block; dim-lane u owns
// dims [4u,4u+4) and [64+4u,64+4u+8... +4). K/V loads: each instruction is
// 4 contiguous 256 B segments (fully-used 64 B lines).
// Softmax is batched PER 16-TOKEN BLOCK: one block-max + one o-rescale per
// block (vs per-token), exps in log2 domain (log2e folded into q prescale).
// ---------------------------------------------------------------------------
__global__ __launch_bounds__(256, 3)
void attn_partial_kernel(const float* __restrict__ q,
                         const float* __restrict__ kcache,
                         const float* __restrict__ vcache,
                         const int*   __restrict__ btab,
                         const int*   __restrict__ lens,
                         float*       __restrict__ part)
{
    const int chunk = blockIdx.x;
    const int kvh   = blockIdx.y;
    const int seq   = blockIdx.z;

    const int len = lens[seq];
    if (chunk * CHUNK_TOKENS >= len) return;     // dead chunk, never read

    const int tid  = threadIdx.x;
    const int wave = tid >> 6;
    const int lane = tid & 63;
    const int g    = lane >> 4;                  // token sub-group 0..3
    const int u    = lane & 15;                  // dim lane 0..15

    // 1/sqrt(128) * log2(e): scores live in log2 domain -> exp2f everywhere
    const float qs = 0.08838834764831845f * 1.44269504088896340736f;

    float4 qa[GROUPS], qb[GROUPS];
    const float* qbase = q + ((size_t)seq * NUM_HEADS + (size_t)kvh * GROUPS) * HEAD_DIM;
#pragma unroll
    for (int h = 0; h < GROUPS; ++h) {
        float4 t = *(const float4*)(qbase + h * HEAD_DIM + 4 * u);
        qa[h] = make_float4(t.x * qs, t.y * qs, t.z * qs, t.w * qs);
        t = *(const float4*)(qbase + h * HEAD_DIM + 64 + 4 * u);
        qb[h] = make_float4(t.x * qs, t.y * qs, t.z * qs, t.w * qs);
    }

    float  m[GROUPS], l[GROUPS];
    float4 oa[GROUPS], ob[GROUPS];
#pragma unroll
    for (int h = 0; h < GROUPS; ++h) {
        m[h] = -INFINITY; l[h] = 0.f;
        oa[h] = make_float4(0.f, 0.f, 0.f, 0.f);
        ob[h] = make_float4(0.f, 0.f, 0.f, 0.f);
    }

    const int nblk   = (len + BLOCK_SIZE - 1) / BLOCK_SIZE;
    const int bstart = chunk * CHUNK_BLOCKS;
    const int bend   = min(bstart + CHUNK_BLOCKS, nblk);

    for (int b = bstart + wave; b < bend; b += 4) {
        const int phys = btab[seq * BLOCKS_PER_SEQ + b];
        const size_t slice = ((size_t)phys * KV_HEADS + kvh) * (BLOCK_SIZE * HEAD_DIM);
        const float* kblk = kcache + slice;
        const float* vblk = vcache + slice;

        float  s[4][GROUPS];
        float4 va[4], vb[4];
#pragma unroll
        for (int j = 0; j < 4; ++j) {            // batch of 4 tokens: 4j+g
            const int off = (4 * j + g) * HEAD_DIM + 4 * u;
            float4 ka = *(const float4*)(kblk + off);
            float4 kb = *(const float4*)(kblk + off + 64);
            va[j] = *(const float4*)(vblk + off);
            vb[j] = *(const float4*)(vblk + off + 64);
#pragma unroll
            for (int h = 0; h < GROUPS; ++h) {
                s[j][h] = ka.x * qa[h].x + ka.y * qa[h].y + ka.z * qa[h].z + ka.w * qa[h].w
                        + kb.x * qb[h].x + kb.y * qb[h].y + kb.z * qb[h].z + kb.w * qb[h].w;
            }
        }

        // butterfly over the 16 dim-lanes: reduces 4 tokens x 4 heads at once
#pragma unroll
        for (int d = 1; d < 16; d <<= 1) {
#pragma unroll
            for (int j = 0; j < 4; ++j)
#pragma unroll
                for (int h = 0; h < GROUPS; ++h)
                    s[j][h] += __shfl_xor(s[j][h], d, 64);
        }

        // mask tokens past len (last block only); exp2(-inf)=0 downstream
        const int tb = b * BLOCK_SIZE + g;
#pragma unroll
        for (int j = 0; j < 4; ++j) {
            if (tb + 4 * j >= len) {
#pragma unroll
                for (int h = 0; h < GROUPS; ++h) s[j][h] = -INFINITY;
            }
        }

        // ONE softmax rescale per 16-token block
#pragma unroll
        for (int h = 0; h < GROUPS; ++h) {
            float bm = fmaxf(fmaxf(s[0][h], s[1][h]), fmaxf(s[2][h], s[3][h]));
            bm = fmaxf(bm, __shfl_xor(bm, 16, 64));
            bm = fmaxf(bm, __shfl_xor(bm, 32, 64));     // block max, wave-uniform
            const float mn    = fmaxf(m[h], bm);        // finite (>=1 valid token)
            const float alpha = exp2f(m[h] - mn);       // first block: exp2(-inf)=0
            l[h] *= alpha;
            oa[h].x *= alpha; oa[h].y *= alpha; oa[h].z *= alpha; oa[h].w *= alpha;
            ob[h].x *= alpha; ob[h].y *= alpha; ob[h].z *= alpha; ob[h].w *= alpha;
            m[h] = mn;
        }

        // p = exp2(s - m); accumulate l (uniform over u) and o (per-dim)
#pragma unroll
        for (int j = 0; j < 4; ++j) {
#pragma unroll
            for (int h = 0; h < GROUPS; ++h) {
                const float p = exp2f(s[j][h] - m[h]);
                l[h] += p;
                oa[h].x += p * va[j].x; oa[h].y += p * va[j].y;
                oa[h].z += p * va[j].z; oa[h].w += p * va[j].w;
                ob[h].x += p * vb[j].x; ob[h].y += p * vb[j].y;
                ob[h].z += p * vb[j].z; ob[h].w += p * vb[j].w;
            }
        }
    }

    // ---- merge the 4 token-groups (lanes xor 16, 32); guard empty groups ----
#pragma unroll
    for (int d = 16; d <= 32; d <<= 1) {
#pragma unroll
        for (int h = 0; h < GROUPS; ++h) {
            const float mo = __shfl_xor(m[h], d, 64);
            const float mn = fmaxf(m[h], mo);
            const float w  = (m[h] == -INFINITY) ? 0.f : exp2f(m[h] - mn);
            float ls = l[h] * w;
            l[h] = ls + __shfl_xor(ls, d, 64);
            oa[h].x *= w; oa[h].y *= w; oa[h].z *= w; oa[h].w *= w;
            ob[h].x *= w; ob[h].y *= w; ob[h].z *= w; ob[h].w *= w;
            oa[h].x += __shfl_xor(oa[h].x, d, 64);
            oa[h].y += __shfl_xor(oa[h].y, d, 64);
            oa[h].z += __shfl_xor(oa[h].z, d, 64);
            oa[h].w += __shfl_xor(oa[h].w, d, 64);
            ob[h].x += __shfl_xor(ob[h].x, d, 64);
            ob[h].y += __shfl_xor(ob[h].y, d, 64);
            ob[h].z += __shfl_xor(ob[h].z, d, 64);
            ob[h].w += __shfl_xor(ob[h].w, d, 64);
            m[h] = mn;
        }
    }

    // ---- merge the 4 waves through LDS ----
    __shared__ float o_lds[4][GROUPS][HEAD_DIM];  // 8 KB
    __shared__ float m_lds[4][GROUPS];
    __shared__ float l_lds[4][GROUPS];
    if (g == 0) {
#pragma unroll
        for (int h = 0; h < GROUPS; ++h) {
            *(float4*)&o_lds[wave][h][4 * u]      = oa[h];
            *(float4*)&o_lds[wave][h][64 + 4 * u] = ob[h];
        }
        if (u == 0) {
#pragma unroll
            for (int h = 0; h < GROUPS; ++h) { m_lds[wave][h] = m[h]; l_lds[wave][h] = l[h]; }
        }
    }
    __syncthreads();

    float* rec = part + (((size_t)(seq * KV_HEADS + kvh)) * NCHUNK + chunk) * REC_STRIDE;
#pragma unroll
    for (int r = 0; r < 2; ++r) {
        const int e = tid + r * 256;              // 0..511 over (head, dim)
        const int h = e >> 7;
        const int d = e & 127;
        float mstar = fmaxf(fmaxf(m_lds[0][h], m_lds[1][h]),
                            fmaxf(m_lds[2][h], m_lds[3][h]));   // finite: wave0 live
        float num = 0.f, L = 0.f;
#pragma unroll
        for (int w = 0; w < 4; ++w) {
            float mw = m_lds[w][h];
            float ww = (mw == -INFINITY) ? 0.f : exp2f(mw - mstar);
            num += o_lds[w][h][d] * ww;
            L   += l_lds[w][h] * ww;
        }
        rec[e] = num;                             // unnormalized output
        if (d == 0) { rec[512 + h] = mstar; rec[516 + h] = L; }
    }
}

// ---------------------------------------------------------------------------
// Kernel 2: merge the <=8 chunk partials per (seq, kvh) and normalize.
// ---------------------------------------------------------------------------
__global__ __launch_bounds__(256)
void attn_reduce_kernel(const float* __restrict__ part,
                        const int*   __restrict__ lens,
                        float*       __restrict__ out)
{
    const int kvh = blockIdx.x & (KV_HEADS - 1);
    const int seq = blockIdx.x / KV_HEADS;
    const int len = lens[seq];
    const int nlive = (len + CHUNK_TOKENS - 1) / CHUNK_TOKENS;   // >= 1

    const float* base = part + ((size_t)(seq * KV_HEADS + kvh)) * NCHUNK * REC_STRIDE;
    const int tid = threadIdx.x;

#pragma unroll
    for (int r = 0; r < 2; ++r) {
        const int e = tid + r * 256;
        const int h = e >> 7;
        const int d = e & 127;

        float mstar = -INFINITY;
        for (int ch = 0; ch < nlive; ++ch)
            mstar = fmaxf(mstar, base[ch * REC_STRIDE + 512 + h]);

        float num = 0.f, L = 0.f;
        for (int ch = 0; ch < nlive; ++ch) {
            const float* r0 = base + ch * REC_STRIDE;
            float ww = exp2f(r0[512 + h] - mstar);   // live chunks have finite m
            num += r0[e] * ww;
            L   += r0[516 + h] * ww;
        }
        out[(size_t)seq * (NUM_HEADS * HEAD_DIM) + (kvh * GROUPS + h) * HEAD_DIM + d] = num / L;
    }
}

extern "C" void kernel_launch(void* const* d_in, const int* in_sizes, int n_in,
                              void* d_out, int out_size, void* d_ws, size_t ws_size,
                              hipStream_t stream) {
    const float* q    = (const float*)d_in[0];
    const float* kc   = (const float*)d_in[1];
    const float* vc   = (const float*)d_in[2];
    const int*   bt   = (const int*)d_in[3];
    const int*   lens = (const int*)d_in[4];
    float* out  = (float*)d_out;
    float* part = (float*)d_ws;   // 64*8*8*520*4 B = 8.5 MB of scratch

    dim3 g1(NCHUNK, KV_HEADS, BSZ);
    attn_partial_kernel<<<g1, 256, 0, stream>>>(q, kc, vc, bt, lens, part);

    dim3 g2(BSZ * KV_HEADS);
    attn_reduce_kernel<<<g2, 256, 0, stream>>>(part, lens, out);
}

// Round 3
// 920.685 us; speedup vs baseline: 1.0774x; 1.0206x over previous
//
#include <hip/hip_runtime.h>
#include <math.h>

// Problem constants (match reference)
#define NUM_HEADS 32
#define KV_HEADS 8
#define GROUPS 4            // NUM_HEADS / KV_HEADS
#define HEAD_DIM 128
#define BLOCK_SIZE 16
#define MAX_CTX 2048
#define BSZ 64
#define BLOCKS_PER_SEQ 128  // MAX_CTX / BLOCK_SIZE

// Flash-decoding split
#define CHUNK_BLOCKS 16
#define CHUNK_TOKENS (CHUNK_BLOCKS * BLOCK_SIZE)   // 256
#define NCHUNK (MAX_CTX / CHUNK_TOKENS)            // 8
#define REC_STRIDE 520      // 4*128 o + 4 m + 4 l floats per partial record

// ---------------------------------------------------------------------------
// DPP rotate-allreduce within a 16-lane DPP row (pure VALU, no DS pipe).
// After 4 ror-adds every lane of the row holds the full 16-lane sum.
// ---------------------------------------------------------------------------
template <int CTRL>
__device__ __forceinline__ float dpp_add(float x) {
    int y = __builtin_amdgcn_update_dpp(0, __float_as_int(x), CTRL, 0xF, 0xF, true);
    return x + __int_as_float(y);
}
__device__ __forceinline__ float row_allsum(float x) {
    x = dpp_add<0x128>(x);   // row_ror:8
    x = dpp_add<0x124>(x);   // row_ror:4
    x = dpp_add<0x122>(x);   // row_ror:2
    x = dpp_add<0x121>(x);   // row_ror:1
    return x;
}

// ---------------------------------------------------------------------------
// Kernel 1: per-(seq, kvh, chunk) partials. 256 threads = 4 waves; wave w
// handles blocks bstart+w, +4, +8, +12. Lane layout: lane = 16*g + u.
// Row g (a DPP row) owns tokens 4j+g of each block; dim-lane u owns float4s
// at dims [4u,4u+4) and [64+4u, 64+4u+4). Every K/V load instruction covers
// 4 contiguous 256 B segments => fully-used 64 B lines.
// Softmax state (m,l,o) is PER ROW: no cross-lane ops at all in the hot
// loop (dot reduce = DPP rotate-adds); rows merge once at chunk end.
// ---------------------------------------------------------------------------
__global__ __launch_bounds__(256, 3)
void attn_partial_kernel(const float* __restrict__ q,
                         const float* __restrict__ kcache,
                         const float* __restrict__ vcache,
                         const int*   __restrict__ btab,
                         const int*   __restrict__ lens,
                         float*       __restrict__ part)
{
    const int chunk = blockIdx.x;
    const int kvh   = blockIdx.y;
    const int seq   = blockIdx.z;

    const int len = lens[seq];
    if (chunk * CHUNK_TOKENS >= len) return;     // dead chunk, never read

    const int tid  = threadIdx.x;
    const int wave = tid >> 6;
    const int lane = tid & 63;
    const int g    = lane >> 4;                  // token row 0..3
    const int u    = lane & 15;                  // dim lane 0..15

    // 1/sqrt(128) * log2(e): scores live in log2 domain -> exp2f everywhere
    const float qs = 0.08838834764831845f * 1.44269504088896340736f;

    float4 qa[GROUPS], qb[GROUPS];
    const float* qbase = q + ((size_t)seq * NUM_HEADS + (size_t)kvh * GROUPS) * HEAD_DIM;
#pragma unroll
    for (int h = 0; h < GROUPS; ++h) {
        float4 t = *(const float4*)(qbase + h * HEAD_DIM + 4 * u);
        qa[h] = make_float4(t.x * qs, t.y * qs, t.z * qs, t.w * qs);
        t = *(const float4*)(qbase + h * HEAD_DIM + 64 + 4 * u);
        qb[h] = make_float4(t.x * qs, t.y * qs, t.z * qs, t.w * qs);
    }

    float  m[GROUPS], l[GROUPS];
    float4 oa[GROUPS], ob[GROUPS];
#pragma unroll
    for (int h = 0; h < GROUPS; ++h) {
        m[h] = -INFINITY; l[h] = 0.f;
        oa[h] = make_float4(0.f, 0.f, 0.f, 0.f);
        ob[h] = make_float4(0.f, 0.f, 0.f, 0.f);
    }

    const int nblk   = (len + BLOCK_SIZE - 1) / BLOCK_SIZE;
    const int bstart = chunk * CHUNK_BLOCKS;
    const int bend   = min(bstart + CHUNK_BLOCKS, nblk);

    // Hoist the wave's block-table entries (indices always <= 127, in-range)
    int physv[4];
#pragma unroll
    for (int k = 0; k < 4; ++k)
        physv[k] = btab[seq * BLOCKS_PER_SEQ + bstart + wave + 4 * k];

#pragma unroll 1
    for (int k = 0; k < 4; ++k) {
        const int b = bstart + wave + 4 * k;
        if (b >= bend) break;
        const size_t slice = ((size_t)physv[k] * KV_HEADS + kvh) * (BLOCK_SIZE * HEAD_DIM);
        const float* kblk = kcache + slice;
        const float* vblk = vcache + slice;

        float  s[4][GROUPS];
        float4 va[4], vb[4];
#pragma unroll
        for (int j = 0; j < 4; ++j) {            // tokens 4j+g
            const int off = (4 * j + g) * HEAD_DIM + 4 * u;
            float4 ka = *(const float4*)(kblk + off);
            float4 kb = *(const float4*)(kblk + off + 64);
            va[j] = *(const float4*)(vblk + off);
            vb[j] = *(const float4*)(vblk + off + 64);
#pragma unroll
            for (int h = 0; h < GROUPS; ++h) {
                s[j][h] = ka.x * qa[h].x + ka.y * qa[h].y + ka.z * qa[h].z + ka.w * qa[h].w
                        + kb.x * qb[h].x + kb.y * qb[h].y + kb.z * qb[h].z + kb.w * qb[h].w;
            }
        }

        // DPP allreduce over the 16 dim-lanes: all lanes get full dot
#pragma unroll
        for (int j = 0; j < 4; ++j)
#pragma unroll
            for (int h = 0; h < GROUPS; ++h)
                s[j][h] = row_allsum(s[j][h]);

        // mask tokens past len (row-uniform); exp2(-inf)=0 downstream
        const int tb = b * BLOCK_SIZE + g;
#pragma unroll
        for (int j = 0; j < 4; ++j) {
            if (tb + 4 * j >= len) {
#pragma unroll
                for (int h = 0; h < GROUPS; ++h) s[j][h] = -INFINITY;
            }
        }

        // per-row online softmax: one rescale per 16-token block, no shfl
#pragma unroll
        for (int h = 0; h < GROUPS; ++h) {
            const float bm = fmaxf(fmaxf(s[0][h], s[1][h]), fmaxf(s[2][h], s[3][h]));
            const float mn = fmaxf(m[h], bm);
            if (mn > -INFINITY) {                // row has >=1 valid token so far
                const float alpha = exp2f(m[h] - mn);   // m=-inf -> 0, mn finite
                m[h] = mn;
                float lh = l[h] * alpha;
                oa[h].x *= alpha; oa[h].y *= alpha; oa[h].z *= alpha; oa[h].w *= alpha;
                ob[h].x *= alpha; ob[h].y *= alpha; ob[h].z *= alpha; ob[h].w *= alpha;
#pragma unroll
                for (int j = 0; j < 4; ++j) {
                    const float p = exp2f(s[j][h] - mn);   // masked: exp2(-inf)=0
                    lh += p;
                    oa[h].x += p * va[j].x; oa[h].y += p * va[j].y;
                    oa[h].z += p * va[j].z; oa[h].w += p * va[j].w;
                    ob[h].x += p * vb[j].x; ob[h].y += p * vb[j].y;
                    ob[h].z += p * vb[j].z; ob[h].w += p * vb[j].w;
                }
                l[h] = lh;
            }
        }
    }

    // ---- merge the 4 rows (lanes xor 16, 32); guard empty rows ----
#pragma unroll
    for (int d = 16; d <= 32; d <<= 1) {
#pragma unroll
        for (int h = 0; h < GROUPS; ++h) {
            const float mo = __shfl_xor(m[h], d, 64);
            const float mn = fmaxf(m[h], mo);
            const float w  = (m[h] == -INFINITY) ? 0.f : exp2f(m[h] - mn);
            float ls = l[h] * w;
            l[h] = ls + __shfl_xor(ls, d, 64);
            oa[h].x *= w; oa[h].y *= w; oa[h].z *= w; oa[h].w *= w;
            ob[h].x *= w; ob[h].y *= w; ob[h].z *= w; ob[h].w *= w;
            oa[h].x += __shfl_xor(oa[h].x, d, 64);
            oa[h].y += __shfl_xor(oa[h].y, d, 64);
            oa[h].z += __shfl_xor(oa[h].z, d, 64);
            oa[h].w += __shfl_xor(oa[h].w, d, 64);
            ob[h].x += __shfl_xor(ob[h].x, d, 64);
            ob[h].y += __shfl_xor(ob[h].y, d, 64);
            ob[h].z += __shfl_xor(ob[h].z, d, 64);
            ob[h].w += __shfl_xor(ob[h].w, d, 64);
            m[h] = mn;
        }
    }

    // ---- merge the 4 waves through LDS ----
    __shared__ float o_lds[4][GROUPS][HEAD_DIM];  // 8 KB
    __shared__ float m_lds[4][GROUPS];
    __shared__ float l_lds[4][GROUPS];
    if (g == 0) {
#pragma unroll
        for (int h = 0; h < GROUPS; ++h) {
            *(float4*)&o_lds[wave][h][4 * u]      = oa[h];
            *(float4*)&o_lds[wave][h][64 + 4 * u] = ob[h];
        }
        if (u == 0) {
#pragma unroll
            for (int h = 0; h < GROUPS; ++h) { m_lds[wave][h] = m[h]; l_lds[wave][h] = l[h]; }
        }
    }
    __syncthreads();

    float* rec = part + (((size_t)(seq * KV_HEADS + kvh)) * NCHUNK + chunk) * REC_STRIDE;
#pragma unroll
    for (int r = 0; r < 2; ++r) {
        const int e = tid + r * 256;              // 0..511 over (head, dim)
        const int h = e >> 7;
        const int d = e & 127;
        float mstar = fmaxf(fmaxf(m_lds[0][h], m_lds[1][h]),
                            fmaxf(m_lds[2][h], m_lds[3][h]));   // finite: wave0 live
        float num = 0.f, L = 0.f;
#pragma unroll
        for (int w = 0; w < 4; ++w) {
            float mw = m_lds[w][h];
            float ww = (mw == -INFINITY) ? 0.f : exp2f(mw - mstar);
            num += o_lds[w][h][d] * ww;
            L   += l_lds[w][h] * ww;
        }
        rec[e] = num;                             // unnormalized output
        if (d == 0) { rec[512 + h] = mstar; rec[516 + h] = L; }
    }
}

// ---------------------------------------------------------------------------
// Kernel 2: merge the <=8 chunk partials per (seq, kvh) and normalize.
// ---------------------------------------------------------------------------
__global__ __launch_bounds__(256)
void attn_reduce_kernel(const float* __restrict__ part,
                        const int*   __restrict__ lens,
                        float*       __restrict__ out)
{
    const int kvh = blockIdx.x & (KV_HEADS - 1);
    const int seq = blockIdx.x / KV_HEADS;
    const int len = lens[seq];
    const int nlive = (len + CHUNK_TOKENS - 1) / CHUNK_TOKENS;   // >= 1

    const float* base = part + ((size_t)(seq * KV_HEADS + kvh)) * NCHUNK * REC_STRIDE;
    const int tid = threadIdx.x;

#pragma unroll
    for (int r = 0; r < 2; ++r) {
        const int e = tid + r * 256;
        const int h = e >> 7;
        const int d = e & 127;

        float mstar = -INFINITY;
        for (int ch = 0; ch < nlive; ++ch)
            mstar = fmaxf(mstar, base[ch * REC_STRIDE + 512 + h]);

        float num = 0.f, L = 0.f;
        for (int ch = 0; ch < nlive; ++ch) {
            const float* r0 = base + ch * REC_STRIDE;
            float ww = exp2f(r0[512 + h] - mstar);   // live chunks have finite m
            num += r0[e] * ww;
            L   += r0[516 + h] * ww;
        }
        out[(size_t)seq * (NUM_HEADS * HEAD_DIM) + (kvh * GROUPS + h) * HEAD_DIM + d] = num / L;
    }
}

extern "C" void kernel_launch(void* const* d_in, const int* in_sizes, int n_in,
                              void* d_out, int out_size, void* d_ws, size_t ws_size,
                              hipStream_t stream) {
    const float* q    = (const float*)d_in[0];
    const float* kc   = (const float*)d_in[1];
    const float* vc   = (const float*)d_in[2];
    const int*   bt   = (const int*)d_in[3];
    const int*   lens = (const int*)d_in[4];
    float* out  = (float*)d_out;
    float* part = (float*)d_ws;   // 64*8*8*520*4 B = 8.5 MB of scratch

    dim3 g1(NCHUNK, KV_HEADS, BSZ);
    attn_partial_kernel<<<g1, 256, 0, stream>>>(q, kc, vc, bt, lens, part);

    dim3 g2(BSZ * KV_HEADS);
    attn_reduce_kernel<<<g2, 256, 0, stream>>>(part, lens, out);
}